// Round 6
// baseline (110.842 us; speedup 1.0000x reference)
//
#include <hip/hip_runtime.h>
#include <hip/hip_cooperative_groups.h>
#include <stdint.h>

namespace cg = cooperative_groups;

#define NEXP 9
#define CAP 131072               // per-expert bucket capacity (mean ~116.5k, +46 sigma)
#define NCHUNK 28                // 28 chunks x 1024B = 28KB per expert table
#define TBL_BYTES (NCHUNK * 1024)
#define RBLK 4096                // samples per block in route phase
#define POSPAD 16                // ints between counters (64B)
#define FGRID 256                // cooperative grid (1 block/CU guaranteed)
#define FTHR 512

typedef float f32x4 __attribute__((ext_vector_type(4)));
typedef float f32x16 __attribute__((ext_vector_type(16)));
typedef _Float16 f16x8 __attribute__((ext_vector_type(8)));

struct alignas(16) I4 { int a, b, c, d; };
struct alignas(64) Q4 { f32x4 a, b, c, d; };

__device__ __forceinline__ int pk(float a, float b) {
    return __builtin_bit_cast(int, __builtin_amdgcn_cvt_pkrtz(a, b));
}
__device__ __forceinline__ f32x16 zero16() {
    f32x16 z;
#pragma unroll
    for (int r = 0; r < 16; ++r) z[r] = 0.f;
    return z;
}

__device__ __forceinline__ int expert_of(float fr) {
    const float frs[NEXP] = {1.f, 2.f, 4.f, 8.f, 16.f, 25.f, 36.f, 50.f, 75.f};
    int k = 0;
    float best = fabsf(fr - frs[0]);
#pragma unroll
    for (int e = 1; e < NEXP; ++e) {
        float d = fabsf(fr - frs[e]);
        if (d < best) { best = d; k = e; }
    }
    return k;
}

// ================= fused cooperative kernel =================
// stage 0: block 0 zeros pos. grid.sync.
// stage 1: each block routes 4096 samples (8 phases x 512 thr); blocks 0..8 then
//          build expert table e=bid in fragment layout. grid.sync.
// stage 2: MLP: 1152 jobs (expert e = j%9, tile = j/9 of 1024 samples), 5 grid-strided
//          iterations; table staged in LDS per job; 28 MFMA per wave per 128 samples.
//
// Table chunk map (chunk = 1024B = 64 lanes x 16B):
//  0      : A1 = W1^T with b1 folded at k=4 (x4=1.0), k>=5 zero
//  1..2   : A2 frags kf=0,1 — K-permuted: frag elem ei,g -> row kf*16+(ei&3)+8*(ei>>2)+4g
//  3..6   : A3 frags (t, kf) = 3+t*2+kf — same K-permutation
//  7..10  : C2 = b2 in D layout
// 11..18  : C3 = b3 in D layout, 11+t*4+c
// 19..26  : W4D = rowsum(W4) in D layout, 19+t*4+c
// 27     : b4s = sum(b4) replicated
__global__ __launch_bounds__(FTHR) void k_fused(const float* __restrict__ feat, int n,
                                                const float* __restrict__ W1, const float* __restrict__ b1,
                                                const float* __restrict__ W2, const float* __restrict__ b2,
                                                const float* __restrict__ W3, const float* __restrict__ b3,
                                                const float* __restrict__ W4, const float* __restrict__ b4,
                                                int* __restrict__ pos,
                                                unsigned* __restrict__ idxb,
                                                uint2* __restrict__ xbuf,
                                                char* __restrict__ tab,
                                                float* __restrict__ out) {
    cg::grid_group gg = cg::this_grid();
    __shared__ char smem[TBL_BYTES];
    int bid = blockIdx.x, tid = threadIdx.x;
    int wid = tid >> 6, lane = tid & 63;

    // ---- stage 0: zero pos ----
    if (bid == 0 && tid < 160) pos[tid] = 0;
    gg.sync();

    // ---- stage 1a: route ----
    {
        int (*wcnt)[NEXP] = (int(*)[NEXP])smem;   // [phase*8+wave][expert]
        for (int base = bid * RBLK; base < n; base += gridDim.x * RBLK) {
            int kk[8], rk[8];
            uint2 xw[8];
#pragma unroll
            for (int r = 0; r < 8; ++r) {
                int i = base + r * FTHR + tid;
                int k = -1;
                uint2 w = {0u, 0u};
                if (i < n) {
                    const float* f = feat + (size_t)i * 5;
                    k = expert_of(f[0]);
                    w.x = (unsigned)pk(f[1], f[2]);
                    w.y = (unsigned)pk(f[3], f[4]);
                }
                kk[r] = k; xw[r] = w;
                unsigned long long myM = 0;
#pragma unroll
                for (int e = 0; e < NEXP; ++e) {
                    unsigned long long mm = __ballot(k == e);
                    if (lane == 0) wcnt[r * 8 + wid][e] = __popcll(mm);
                    if (k == e) myM = mm;
                }
                rk[r] = __popcll(myM & ((1ull << lane) - 1ull));
            }
            __syncthreads();
            // scan: wave w handles experts w, w+8
            for (int e = wid; e < NEXP; e += 8) {
                int v = wcnt[lane][e];
                int s = v;
#pragma unroll
                for (int d = 1; d < 64; d <<= 1) {
                    int t = __shfl_up(s, d, 64);
                    if (lane >= d) s += t;
                }
                int total = __shfl(s, 63, 64);
                int gbase = 0;
                if (lane == 0) gbase = atomicAdd(&pos[e * POSPAD], total);
                gbase = __shfl(gbase, 0, 64);
                wcnt[lane][e] = gbase + (s - v);
            }
            __syncthreads();
#pragma unroll
            for (int r = 0; r < 8; ++r) {
                int k = kk[r];
                if (k >= 0) {
                    int slot = wcnt[r * 8 + wid][k] + rk[r];
                    if (slot < CAP) {
                        int i = base + r * FTHR + tid;
                        idxb[(size_t)k * CAP + slot] = (unsigned)i;
                        xbuf[(size_t)k * CAP + slot] = xw[r];
                    }
                }
            }
            __syncthreads();
        }
    }

    // ---- stage 1b: blocks 0..8 build expert tables ----
    if (bid < NEXP) {
        int e = bid;
        char* T = tab + (size_t)e * TBL_BYTES;
        float (*psum)[8] = (float(*)[8])smem;              // 64x8 floats
        float* rs = (float*)(smem + 2048);                 // 64 floats
        {
            int row = tid >> 3, q = tid & 7;
            const float* w = W4 + (size_t)e * 4096 + row * 64 + q * 8;
            f32x4 va = *(const f32x4*)w;
            f32x4 vb = *(const f32x4*)(w + 4);
            psum[row][q] = va.x + va.y + va.z + va.w + vb.x + vb.y + vb.z + vb.w;
        }
        __syncthreads();
        if (tid < 64) {
            int l = tid, g = l >> 5, m = l & 31;
            {
                float s = 0.f;
#pragma unroll
                for (int q = 0; q < 8; ++q) s += psum[l][q];
                rs[l] = s;
            }
            float bp = b4[e * 64 + l];
#pragma unroll
            for (int d = 1; d < 64; d <<= 1) bp += __shfl_xor(bp, d, 64);

            // A1
            {
                f16x8 v;
#pragma unroll
                for (int ei = 0; ei < 8; ++ei) {
                    int k = g * 8 + ei;
                    float w = (k < 4) ? W1[e * 128 + k * 32 + m] : (k == 4 ? b1[e * 32 + m] : 0.f);
                    v[ei] = (_Float16)w;
                }
                *(f16x8*)(T + 0 * 1024 + l * 16) = v;
            }
            // A2 (K-permuted)
#pragma unroll
            for (int kf = 0; kf < 2; ++kf) {
                f16x8 v;
#pragma unroll
                for (int ei = 0; ei < 8; ++ei) {
                    int row = kf * 16 + (ei & 3) + 8 * (ei >> 2) + 4 * g;
                    v[ei] = (_Float16)W2[e * 1024 + row * 32 + m];
                }
                *(f16x8*)(T + (1 + kf) * 1024 + l * 16) = v;
            }
            // A3 (K-permuted)
#pragma unroll
            for (int t = 0; t < 2; ++t)
#pragma unroll
                for (int kf = 0; kf < 2; ++kf) {
                    f16x8 v;
#pragma unroll
                    for (int ei = 0; ei < 8; ++ei) {
                        int row = kf * 16 + (ei & 3) + 8 * (ei >> 2) + 4 * g;
                        v[ei] = (_Float16)W3[e * 2048 + row * 64 + t * 32 + m];
                    }
                    *(f16x8*)(T + (3 + t * 2 + kf) * 1024 + l * 16) = v;
                }
            // C2
#pragma unroll
            for (int c = 0; c < 4; ++c) {
                f32x4 v;
#pragma unroll
                for (int j = 0; j < 4; ++j) {
                    int r = c * 4 + j;
                    int row = (r & 3) + 8 * (r >> 2) + 4 * g;
                    v[j] = b2[e * 32 + row];
                }
                *(f32x4*)(T + (7 + c) * 1024 + l * 16) = v;
            }
            // C3
#pragma unroll
            for (int t = 0; t < 2; ++t)
#pragma unroll
                for (int c = 0; c < 4; ++c) {
                    f32x4 v;
#pragma unroll
                    for (int j = 0; j < 4; ++j) {
                        int r = c * 4 + j;
                        int row = t * 32 + (r & 3) + 8 * (r >> 2) + 4 * g;
                        v[j] = b3[e * 64 + row];
                    }
                    *(f32x4*)(T + (11 + t * 4 + c) * 1024 + l * 16) = v;
                }
            // W4D
#pragma unroll
            for (int t = 0; t < 2; ++t)
#pragma unroll
                for (int c = 0; c < 4; ++c) {
                    f32x4 v;
#pragma unroll
                    for (int j = 0; j < 4; ++j) {
                        int r = c * 4 + j;
                        int row = t * 32 + (r & 3) + 8 * (r >> 2) + 4 * g;
                        v[j] = rs[row];
                    }
                    *(f32x4*)(T + (19 + t * 4 + c) * 1024 + l * 16) = v;
                }
            f32x4 bb = {bp, bp, bp, bp};
            *(f32x4*)(T + 27 * 1024 + l * 16) = bb;
        }
    }
    gg.sync();

    // ---- stage 2: MLP over 1152 jobs of 1024 samples ----
    const int njobs = NEXP * (CAP / 1024);      // 1152
    int g = lane >> 5, m = lane & 31;
    for (int it = 0; it < 5; ++it) {
        int j = bid + gridDim.x * it;
        if (j >= njobs) break;
        int e = j % NEXP, tile = j / NEXP;
        int count = pos[e * POSPAD];
        count = count < CAP ? count : CAP;
        int jbase = tile * 1024;
        if (jbase >= count) continue;           // block-uniform

        __syncthreads();
        {   // stage table into LDS (28KB, 512 thr x up to 4 f32x4)
            const f32x4* T = (const f32x4*)(tab + (size_t)e * TBL_BYTES);
            f32x4* S = (f32x4*)smem;
#pragma unroll
            for (int q = 0; q < 4; ++q) {
                int o = q * FTHR + tid;
                if (o < TBL_BYTES / 16) S[o] = T[o];
            }
        }
        __syncthreads();

        int wbase = jbase + wid * 128;
        if (wbase < count) {
            auto ldA = [&](int chunk) -> f16x8 {
                return *(const f16x8*)(smem + chunk * 1024 + lane * 16);
            };
            auto ldC = [&](int chunk) -> f32x16 {
                Q4 q;
                q.a = *(const f32x4*)(smem + (chunk + 0) * 1024 + lane * 16);
                q.b = *(const f32x4*)(smem + (chunk + 1) * 1024 + lane * 16);
                q.c = *(const f32x4*)(smem + (chunk + 2) * 1024 + lane * 16);
                q.d = *(const f32x4*)(smem + (chunk + 3) * 1024 + lane * 16);
                return __builtin_bit_cast(f32x16, q);
            };
            f16x8 A1 = ldA(0);
            f16x8 A2a = ldA(1), A2b = ldA(2);
            f16x8 A30a = ldA(3), A30b = ldA(4), A31a = ldA(5), A31b = ldA(6);
            f32x16 C2 = ldC(7);
            f32x16 C30 = ldC(11), C31 = ldC(15);
            f32x16 W40 = ldC(19), W41 = ldC(23);
            float b4v = *(const float*)(smem + 27 * 1024);

            uint2 xt[4];
#pragma unroll
            for (int t = 0; t < 4; ++t) {
                int sl = wbase + t * 32 + m;
                uint2 w = {0u, 0u};
                if (sl < count) w = xbuf[(size_t)e * CAP + sl];
                xt[t] = w;
            }
            int sA = wbase + g * 64 + m;
            int sB = wbase + g * 64 + 32 + m;
            bool vA = sA < count, vB = sB < count;
            unsigned iA = vA ? idxb[(size_t)e * CAP + sA] : 0u;
            unsigned iB = vB ? idxb[(size_t)e * CAP + sB] : 0u;

            float res[4];
#pragma unroll
            for (int t = 0; t < 4; ++t) {
                I4 b1i = {g ? 0 : (int)xt[t].x, g ? 0 : (int)xt[t].y, g ? 0 : 0x3C00, 0};
                f16x8 B1 = __builtin_bit_cast(f16x8, b1i);

                f32x16 d1 = __builtin_amdgcn_mfma_f32_32x32x16_f16(A1, B1, zero16(), 0, 0, 0);
#pragma unroll
                for (int r = 0; r < 16; ++r) d1[r] = fmaxf(d1[r], 0.f);
                I4 p0 = {pk(d1[0], d1[1]), pk(d1[2], d1[3]), pk(d1[4], d1[5]), pk(d1[6], d1[7])};
                I4 p1 = {pk(d1[8], d1[9]), pk(d1[10], d1[11]), pk(d1[12], d1[13]), pk(d1[14], d1[15])};
                f16x8 B2a = __builtin_bit_cast(f16x8, p0);
                f16x8 B2b = __builtin_bit_cast(f16x8, p1);

                f32x16 d2 = __builtin_amdgcn_mfma_f32_32x32x16_f16(A2a, B2a, C2, 0, 0, 0);
                d2 = __builtin_amdgcn_mfma_f32_32x32x16_f16(A2b, B2b, d2, 0, 0, 0);
#pragma unroll
                for (int r = 0; r < 16; ++r) d2[r] = fmaxf(d2[r], 0.f);
                I4 q0 = {pk(d2[0], d2[1]), pk(d2[2], d2[3]), pk(d2[4], d2[5]), pk(d2[6], d2[7])};
                I4 q1 = {pk(d2[8], d2[9]), pk(d2[10], d2[11]), pk(d2[12], d2[13]), pk(d2[14], d2[15])};
                f16x8 B3a = __builtin_bit_cast(f16x8, q0);
                f16x8 B3b = __builtin_bit_cast(f16x8, q1);

                float acc = 0.f;
                {
                    f32x16 d3 = __builtin_amdgcn_mfma_f32_32x32x16_f16(A30a, B3a, C30, 0, 0, 0);
                    d3 = __builtin_amdgcn_mfma_f32_32x32x16_f16(A30b, B3b, d3, 0, 0, 0);
#pragma unroll
                    for (int r = 0; r < 16; ++r) acc += fmaxf(d3[r], 0.f) * W40[r];
                }
                {
                    f32x16 d3 = __builtin_amdgcn_mfma_f32_32x32x16_f16(A31a, B3a, C31, 0, 0, 0);
                    d3 = __builtin_amdgcn_mfma_f32_32x32x16_f16(A31b, B3b, d3, 0, 0, 0);
#pragma unroll
                    for (int r = 0; r < 16; ++r) acc += fmaxf(d3[r], 0.f) * W41[r];
                }
                acc += __shfl_xor(acc, 32, 64);
                res[t] = acc + b4v;
            }
            float rA = g ? res[2] : res[0];
            float rB = g ? res[3] : res[1];
            if (vA) out[iA] = rA;
            if (vB) out[iB] = rB;
        }
    }
}

// ---------------- fallback (ws too small): divergent, correct ----------------
__global__ __launch_bounds__(256) void k_fallback(const float* __restrict__ feat,
                                                  const float* __restrict__ W1, const float* __restrict__ b1,
                                                  const float* __restrict__ W2, const float* __restrict__ b2,
                                                  const float* __restrict__ W3, const float* __restrict__ b3,
                                                  const float* __restrict__ W4, const float* __restrict__ b4,
                                                  float* __restrict__ out, int n) {
    int i = blockIdx.x * 256 + threadIdx.x;
    if (i >= n) return;
    const float* f = feat + (size_t)i * 5;
    int e = expert_of(f[0]);
    float x0 = f[1], x1 = f[2], x2 = f[3], x3 = f[4];
    float h1[32], h2[32], h3[64];
    for (int j = 0; j < 32; ++j) {
        float a = b1[e * 32 + j];
        a += x0 * W1[e * 128 + 0 * 32 + j];
        a += x1 * W1[e * 128 + 1 * 32 + j];
        a += x2 * W1[e * 128 + 2 * 32 + j];
        a += x3 * W1[e * 128 + 3 * 32 + j];
        h1[j] = fmaxf(a, 0.f);
    }
    for (int j = 0; j < 32; ++j) h2[j] = b2[e * 32 + j];
    for (int i2 = 0; i2 < 32; ++i2)
        for (int j = 0; j < 32; ++j) h2[j] += h1[i2] * W2[e * 1024 + i2 * 32 + j];
    for (int j = 0; j < 32; ++j) h2[j] = fmaxf(h2[j], 0.f);
    for (int j = 0; j < 64; ++j) h3[j] = b3[e * 64 + j];
    for (int i2 = 0; i2 < 32; ++i2)
        for (int j = 0; j < 64; ++j) h3[j] += h2[i2] * W3[e * 2048 + i2 * 64 + j];
    float pred = 0.f;
    for (int o = 0; o < 64; ++o) pred += b4[e * 64 + o];
    for (int j = 0; j < 64; ++j) {
        float rsum = 0.f;
        for (int o = 0; o < 64; ++o) rsum += W4[e * 4096 + j * 64 + o];
        pred += fmaxf(h3[j], 0.f) * rsum;
    }
    out[i] = pred;
}

extern "C" void kernel_launch(void* const* d_in, const int* in_sizes, int n_in,
                              void* d_out, int out_size, void* d_ws, size_t ws_size,
                              hipStream_t stream) {
    const float* feat = (const float*)d_in[0];
    const float* W1 = (const float*)d_in[1];
    const float* b1 = (const float*)d_in[2];
    const float* W2 = (const float*)d_in[3];
    const float* b2 = (const float*)d_in[4];
    const float* W3 = (const float*)d_in[5];
    const float* b3 = (const float*)d_in[6];
    const float* W4 = (const float*)d_in[7];
    const float* b4 = (const float*)d_in[8];
    float* out = (float*)d_out;
    int n = in_sizes[0] / 5;

    const size_t off_pos = 0;                                  // 1 KB
    const size_t off_tab = 1024;                               // 9 * 28 KB
    const size_t off_x = off_tab + (size_t)NEXP * TBL_BYTES;   // 9 * CAP * 8 B
    const size_t off_idx = off_x + (size_t)NEXP * CAP * 8;     // 9 * CAP * 4 B
    const size_t need = off_idx + (size_t)NEXP * CAP * 4;

    if (ws_size >= need && n <= CAP * NEXP) {
        char* ws = (char*)d_ws;
        int* pos = (int*)(ws + off_pos);
        char* tab = ws + off_tab;
        uint2* xbuf = (uint2*)(ws + off_x);
        unsigned* idxb = (unsigned*)(ws + off_idx);

        void* args[] = {(void*)&feat, (void*)&n,
                        (void*)&W1, (void*)&b1, (void*)&W2, (void*)&b2,
                        (void*)&W3, (void*)&b3, (void*)&W4, (void*)&b4,
                        (void*)&pos, (void*)&idxb, (void*)&xbuf, (void*)&tab, (void*)&out};
        hipLaunchCooperativeKernel((const void*)k_fused, dim3(FGRID), dim3(FTHR),
                                   args, 0, stream);
    } else {
        k_fallback<<<(n + 255) / 256, 256, 0, stream>>>(feat, W1, b1, W2, b2, W3, b3, W4, b4, out, n);
    }
}

// Round 8
// 47.757 us; speedup vs baseline: 2.3210x; 2.3210x over previous
//
#include <hip/hip_runtime.h>
#include <stdint.h>

#define NEXP 9
#define FTHR 512                 // threads per main block
#define SBLK 1024                // samples per main block (2 phases x 512)
#define PADSLK (SBLK + NEXP * 32)// padded bucket slots (1312)
#define MAXT 48                  // max tiles per block (<= 9 + 1024/32 = 41)
#define TBL_BYTES 7936           // per-expert: 7x1024B A-frags + 768B compact C

typedef float f32x4 __attribute__((ext_vector_type(4)));
typedef float f32x16 __attribute__((ext_vector_type(16)));
typedef _Float16 f16x8 __attribute__((ext_vector_type(8)));

struct alignas(16) I4 { int a, b, c, d; };
struct alignas(64) Q4 { f32x4 a, b, c, d; };

__device__ __forceinline__ int pk(float a, float b) {
    return __builtin_bit_cast(int, __builtin_amdgcn_cvt_pkrtz(a, b));
}
__device__ __forceinline__ f32x16 zero16() {
    f32x16 z;
#pragma unroll
    for (int r = 0; r < 16; ++r) z[r] = 0.f;
    return z;
}

__device__ __forceinline__ int expert_of(float fr) {
    const float frs[NEXP] = {1.f, 2.f, 4.f, 8.f, 16.f, 25.f, 36.f, 50.f, 75.f};
    int k = 0;
    float best = fabsf(fr - frs[0]);
#pragma unroll
    for (int e = 1; e < NEXP; ++e) {
        float d = fabsf(fr - frs[e]);
        if (d < best) { best = d; k = e; }
    }
    return k;
}

// ================= K_prep: per-expert tables (A-frags + compact C) =================
// Per-expert table (TBL_BYTES):
//   0..7167  : 7 chunks x 1024B, f16 A-fragments (chunk = 64 lanes x 16B):
//     0      : A1 = W1^T, b1 folded at k=4 (x4=1.0); g=1 half all-zero
//     1..2   : A2 kf=0,1 — K-permuted: elem ei,g -> row kf*16+(ei&3)+8*(ei>>2)+4g
//     3..6   : A3 (t,kf)=3+t*2+kf — same K-permutation
//   7168..   : compact C floats [mat][32], idx = mat*32 + g*16 + r:
//     mat 0  : C2  = b2[(r&3)+8(r>>2)+4g]
//     mat 1,2: C30/C31 = b3 tiles 0/1
//     mat 3,4: W40/W41 = rowsum(W4) tiles 0/1
//     [160]  : b4s = sum(b4)
__global__ __launch_bounds__(256) void k_prep(const float* __restrict__ W1, const float* __restrict__ b1,
                                              const float* __restrict__ W2, const float* __restrict__ b2,
                                              const float* __restrict__ W3, const float* __restrict__ b3,
                                              const float* __restrict__ W4, const float* __restrict__ b4,
                                              char* __restrict__ tab) {
    int e = blockIdx.x;
    int tid = threadIdx.x;
    char* T = tab + (size_t)e * TBL_BYTES;

    __shared__ float psum[64][4];
    __shared__ float rs2[64];
    __shared__ float b4s_s;
    {   // W4 rowsum partials: 256 thr, each sums 16 floats
        int row = tid >> 2, q = tid & 3;
        const float* w = W4 + (size_t)e * 4096 + row * 64 + q * 16;
        f32x4 a = *(const f32x4*)(w + 0), b = *(const f32x4*)(w + 4);
        f32x4 c = *(const f32x4*)(w + 8), d = *(const f32x4*)(w + 12);
        psum[row][q] = (a.x + a.y + a.z + a.w) + (b.x + b.y + b.z + b.w)
                     + (c.x + c.y + c.z + c.w) + (d.x + d.y + d.z + d.w);
    }
    __syncthreads();
    if (tid < 64) {
        int l = tid, g = l >> 5, m = l & 31;
        rs2[l] = psum[l][0] + psum[l][1] + psum[l][2] + psum[l][3];
        float bp = b4[e * 64 + l];
#pragma unroll
        for (int d = 1; d < 64; d <<= 1) bp += __shfl_xor(bp, d, 64);
        if (l == 0) b4s_s = bp;

        // A1
        {
            f16x8 v;
#pragma unroll
            for (int ei = 0; ei < 8; ++ei) {
                int k = g * 8 + ei;
                float w = (k < 4) ? W1[e * 128 + k * 32 + m] : (k == 4 ? b1[e * 32 + m] : 0.f);
                v[ei] = (_Float16)w;
            }
            *(f16x8*)(T + 0 * 1024 + l * 16) = v;
        }
        // A2 (K-permuted)
#pragma unroll
        for (int kf = 0; kf < 2; ++kf) {
            f16x8 v;
#pragma unroll
            for (int ei = 0; ei < 8; ++ei) {
                int row = kf * 16 + (ei & 3) + 8 * (ei >> 2) + 4 * g;
                v[ei] = (_Float16)W2[e * 1024 + row * 32 + m];
            }
            *(f16x8*)(T + (1 + kf) * 1024 + l * 16) = v;
        }
        // A3 (K-permuted)
#pragma unroll
        for (int t = 0; t < 2; ++t)
#pragma unroll
            for (int kf = 0; kf < 2; ++kf) {
                f16x8 v;
#pragma unroll
                for (int ei = 0; ei < 8; ++ei) {
                    int row = kf * 16 + (ei & 3) + 8 * (ei >> 2) + 4 * g;
                    v[ei] = (_Float16)W3[e * 2048 + row * 64 + t * 32 + m];
                }
                *(f16x8*)(T + (3 + t * 2 + kf) * 1024 + l * 16) = v;
            }
    }
    __syncthreads();
    if (tid < 32) {
        int g = tid >> 4, r = tid & 15;
        int row = (r & 3) + 8 * (r >> 2) + 4 * g;
        float* C = (float*)(T + 7168);
        C[0 * 32 + tid] = b2[e * 32 + row];
        C[1 * 32 + tid] = b3[e * 64 + row];
        C[2 * 32 + tid] = b3[e * 64 + 32 + row];
        C[3 * 32 + tid] = rs2[row];
        C[4 * 32 + tid] = rs2[32 + row];
        if (tid == 0) C[160] = b4s_s;
    }
}

// ================= K_main: block-local bucket + MFMA MLP, one pass =================
__global__ __launch_bounds__(FTHR, 4) void k_main(const float* __restrict__ feat, int n,
                                                  const char* __restrict__ tab,
                                                  float* __restrict__ out) {
    __shared__ uint2 bx[PADSLK];                // packed f16 features per slot (incl. pad)
    __shared__ unsigned short bidx[PADSLK];     // local sample index per slot
    __shared__ int lcnt[NEXP];
    __shared__ int pbase[NEXP];
    __shared__ int wbase[2][8][NEXP];           // [phase][wave][expert] offsets
    __shared__ unsigned char tile_e[MAXT];
    __shared__ short tile_s[MAXT];
    __shared__ unsigned char tile_v[MAXT];
    __shared__ int nt_s;

    int bid = blockIdx.x, tid = threadIdx.x;
    int wid = tid >> 6, lane = tid & 63, g = lane >> 5, m = lane & 31;
    int gbase = bid * SBLK;

    if (tid < NEXP) lcnt[tid] = 0;
    {   // zero the full padded bucket range (pad slots must be benign)
        uint2 z = {0u, 0u};
#pragma unroll
        for (int q = 0; q < 3; ++q) {
            int o = q * FTHR + tid;
            if (o < PADSLK) bx[o] = z;
        }
    }
    __syncthreads();

    // ---- phase 1: classify + per-wave counts ----
    int kk[2], rk[2];
    uint2 xw[2];
#pragma unroll
    for (int r = 0; r < 2; ++r) {
        int i = gbase + r * FTHR + tid;
        int k = -1;
        uint2 w = {0u, 0u};
        if (i < n) {
            const float* f = feat + (size_t)i * 5;
            k = expert_of(f[0]);
            w.x = (unsigned)pk(f[1], f[2]);
            w.y = (unsigned)pk(f[3], f[4]);
        }
        kk[r] = k; xw[r] = w;
        unsigned long long myM = 0;
#pragma unroll
        for (int e = 0; e < NEXP; ++e) {
            unsigned long long mm = __ballot(k == e);
            if (k == e) myM = mm;
            if (lane == 0) {
                int c = __popcll(mm);
                wbase[r][wid][e] = c ? atomicAdd(&lcnt[e], c) : 0;
            }
        }
        rk[r] = __popcll(myM & ((1ull << lane) - 1ull));
    }
    __syncthreads();

    // ---- tile map: padded prefix over experts (thread 0, tiny) ----
    if (tid == 0) {
        int off = 0, t = 0;
        for (int e = 0; e < NEXP; ++e) {
            int c = lcnt[e];
            pbase[e] = off;
            int ntl = (c + 31) >> 5;
            for (int j = 0; j < ntl; ++j) {
                tile_e[t] = (unsigned char)e;
                tile_s[t] = (short)(off + j * 32);
                int v = c - j * 32;
                tile_v[t] = (unsigned char)(v > 32 ? 32 : v);
                ++t;
            }
            off += ntl * 32;
        }
        nt_s = t;
    }
    __syncthreads();

    // ---- phase 2: scatter into LDS buckets ----
#pragma unroll
    for (int r = 0; r < 2; ++r) {
        int k = kk[r];
        if (k >= 0) {
            int slot = pbase[k] + wbase[r][wid][k] + rk[r];
            bx[slot] = xw[r];
            bidx[slot] = (unsigned short)(r * FTHR + tid);
        }
    }
    __syncthreads();

    // ---- MLP: contiguous tile range per wave (A-frag reuse across same-expert runs) ----
    int nt = nt_s;
    int t0 = (wid * nt) >> 3, t1 = ((wid + 1) * nt) >> 3;
    int cur_e = -1;
    f16x8 A1 = {}, A2a = {}, A2b = {}, A30a = {}, A30b = {}, A31a = {}, A31b = {};
    const char* T = tab;
    for (int t = t0; t < t1; ++t) {
        int e = __builtin_amdgcn_readfirstlane((int)tile_e[t]);
        if (e != cur_e) {
            cur_e = e;
            T = tab + (size_t)e * TBL_BYTES;
            A1 = *(const f16x8*)(T + 0 * 1024 + lane * 16);
            A2a = *(const f16x8*)(T + 1 * 1024 + lane * 16);
            A2b = *(const f16x8*)(T + 2 * 1024 + lane * 16);
            A30a = *(const f16x8*)(T + 3 * 1024 + lane * 16);
            A30b = *(const f16x8*)(T + 4 * 1024 + lane * 16);
            A31a = *(const f16x8*)(T + 5 * 1024 + lane * 16);
            A31b = *(const f16x8*)(T + 6 * 1024 + lane * 16);
        }
        const float* Cc = (const float*)(T + 7168) + g * 16;
        auto ldC = [&](int mat) -> f32x16 {
            const float* c = Cc + mat * 32;
            Q4 q;
            q.a = *(const f32x4*)(c + 0);
            q.b = *(const f32x4*)(c + 4);
            q.c = *(const f32x4*)(c + 8);
            q.d = *(const f32x4*)(c + 12);
            return __builtin_bit_cast(f32x16, q);
        };

        int s = tile_s[t], v = tile_v[t];
        uint2 xv = bx[s + m];

        I4 b1i = {g ? 0 : (int)xv.x, g ? 0 : (int)xv.y, g ? 0 : 0x3C00, 0};
        f16x8 B1 = __builtin_bit_cast(f16x8, b1i);

        f32x16 d1 = __builtin_amdgcn_mfma_f32_32x32x16_f16(A1, B1, zero16(), 0, 0, 0);
#pragma unroll
        for (int r = 0; r < 16; ++r) d1[r] = fmaxf(d1[r], 0.f);
        I4 p0 = {pk(d1[0], d1[1]), pk(d1[2], d1[3]), pk(d1[4], d1[5]), pk(d1[6], d1[7])};
        I4 p1 = {pk(d1[8], d1[9]), pk(d1[10], d1[11]), pk(d1[12], d1[13]), pk(d1[14], d1[15])};
        f16x8 B2a = __builtin_bit_cast(f16x8, p0);
        f16x8 B2b = __builtin_bit_cast(f16x8, p1);

        f32x16 d2 = __builtin_amdgcn_mfma_f32_32x32x16_f16(A2a, B2a, ldC(0), 0, 0, 0);
        d2 = __builtin_amdgcn_mfma_f32_32x32x16_f16(A2b, B2b, d2, 0, 0, 0);
#pragma unroll
        for (int r = 0; r < 16; ++r) d2[r] = fmaxf(d2[r], 0.f);
        I4 q0 = {pk(d2[0], d2[1]), pk(d2[2], d2[3]), pk(d2[4], d2[5]), pk(d2[6], d2[7])};
        I4 q1 = {pk(d2[8], d2[9]), pk(d2[10], d2[11]), pk(d2[12], d2[13]), pk(d2[14], d2[15])};
        f16x8 B3a = __builtin_bit_cast(f16x8, q0);
        f16x8 B3b = __builtin_bit_cast(f16x8, q1);

        float acc = 0.f;
        {
            f32x16 d3 = __builtin_amdgcn_mfma_f32_32x32x16_f16(A30a, B3a, ldC(1), 0, 0, 0);
            d3 = __builtin_amdgcn_mfma_f32_32x32x16_f16(A30b, B3b, d3, 0, 0, 0);
            f32x16 w4 = ldC(3);
#pragma unroll
            for (int r = 0; r < 16; ++r) acc += fmaxf(d3[r], 0.f) * w4[r];
        }
        {
            f32x16 d3 = __builtin_amdgcn_mfma_f32_32x32x16_f16(A31a, B3a, ldC(2), 0, 0, 0);
            d3 = __builtin_amdgcn_mfma_f32_32x32x16_f16(A31b, B3b, d3, 0, 0, 0);
            f32x16 w4 = ldC(4);
#pragma unroll
            for (int r = 0; r < 16; ++r) acc += fmaxf(d3[r], 0.f) * w4[r];
        }
        acc += __shfl_xor(acc, 32, 64);
        float rres = acc + *((const float*)(T + 7168) + 160);
        if (!g && m < v) out[gbase + (int)bidx[s + m]] = rres;
    }
}

// ---------------- fallback (ws too small): divergent, correct ----------------
__global__ __launch_bounds__(256) void k_fallback(const float* __restrict__ feat,
                                                  const float* __restrict__ W1, const float* __restrict__ b1,
                                                  const float* __restrict__ W2, const float* __restrict__ b2,
                                                  const float* __restrict__ W3, const float* __restrict__ b3,
                                                  const float* __restrict__ W4, const float* __restrict__ b4,
                                                  float* __restrict__ out, int n) {
    int i = blockIdx.x * 256 + threadIdx.x;
    if (i >= n) return;
    const float* f = feat + (size_t)i * 5;
    int e = expert_of(f[0]);
    float x0 = f[1], x1 = f[2], x2 = f[3], x3 = f[4];
    float h1[32], h2[32], h3[64];
    for (int j = 0; j < 32; ++j) {
        float a = b1[e * 32 + j];
        a += x0 * W1[e * 128 + 0 * 32 + j];
        a += x1 * W1[e * 128 + 1 * 32 + j];
        a += x2 * W1[e * 128 + 2 * 32 + j];
        a += x3 * W1[e * 128 + 3 * 32 + j];
        h1[j] = fmaxf(a, 0.f);
    }
    for (int j = 0; j < 32; ++j) h2[j] = b2[e * 32 + j];
    for (int i2 = 0; i2 < 32; ++i2)
        for (int j = 0; j < 32; ++j) h2[j] += h1[i2] * W2[e * 1024 + i2 * 32 + j];
    for (int j = 0; j < 32; ++j) h2[j] = fmaxf(h2[j], 0.f);
    for (int j = 0; j < 64; ++j) h3[j] = b3[e * 64 + j];
    for (int i2 = 0; i2 < 32; ++i2)
        for (int j = 0; j < 64; ++j) h3[j] += h2[i2] * W3[e * 2048 + i2 * 64 + j];
    float pred = 0.f;
    for (int o = 0; o < 64; ++o) pred += b4[e * 64 + o];
    for (int j = 0; j < 64; ++j) {
        float rsum = 0.f;
        for (int o = 0; o < 64; ++o) rsum += W4[e * 4096 + j * 64 + o];
        pred += fmaxf(h3[j], 0.f) * rsum;
    }
    out[i] = pred;
}

extern "C" void kernel_launch(void* const* d_in, const int* in_sizes, int n_in,
                              void* d_out, int out_size, void* d_ws, size_t ws_size,
                              hipStream_t stream) {
    const float* feat = (const float*)d_in[0];
    const float* W1 = (const float*)d_in[1];
    const float* b1 = (const float*)d_in[2];
    const float* W2 = (const float*)d_in[3];
    const float* b2 = (const float*)d_in[4];
    const float* W3 = (const float*)d_in[5];
    const float* b3 = (const float*)d_in[6];
    const float* W4 = (const float*)d_in[7];
    const float* b4 = (const float*)d_in[8];
    float* out = (float*)d_out;
    int n = in_sizes[0] / 5;

    const size_t need = (size_t)NEXP * TBL_BYTES;

    if (ws_size >= need) {
        char* tab = (char*)d_ws;
        k_prep<<<NEXP, 256, 0, stream>>>(W1, b1, W2, b2, W3, b3, W4, b4, tab);
        int nb = (n + SBLK - 1) / SBLK;
        k_main<<<nb, FTHR, 0, stream>>>(feat, n, tab, out);
    } else {
        k_fallback<<<(n + 255) / 256, 256, 0, stream>>>(feat, W1, b1, W2, b2, W3, b3, W4, b4, out, n);
    }
}

// Round 9
// 33.551 us; speedup vs baseline: 3.3037x; 1.4234x over previous
//
#include <hip/hip_runtime.h>
#include <stdint.h>

#define NEXP 9
#define FTHR 512                 // threads per main block
#define RPH 4                    // classify phases
#define SBLK (FTHR * RPH)        // 2048 samples per main block
#define PADSLK (SBLK + NEXP * 32)// padded bucket slots (2336)
#define MAXT 80                  // max tiles per block (<= 2048/32 + 9 = 73)
#define TBL_BYTES 7936           // per-expert: 7x1024B A-frags + 768B compact C
#define CLS_STRIDE 168           // floats per expert in LDS C-table (161 used)

typedef float f32x4 __attribute__((ext_vector_type(4)));
typedef float f32x16 __attribute__((ext_vector_type(16)));
typedef _Float16 f16x8 __attribute__((ext_vector_type(8)));

struct alignas(16) I4 { int a, b, c, d; };
struct alignas(64) Q4 { f32x4 a, b, c, d; };

__device__ __forceinline__ int pk(float a, float b) {
    return __builtin_bit_cast(int, __builtin_amdgcn_cvt_pkrtz(a, b));
}
__device__ __forceinline__ f32x16 zero16() {
    f32x16 z;
#pragma unroll
    for (int r = 0; r < 16; ++r) z[r] = 0.f;
    return z;
}

__device__ __forceinline__ int expert_of(float fr) {
    const float frs[NEXP] = {1.f, 2.f, 4.f, 8.f, 16.f, 25.f, 36.f, 50.f, 75.f};
    int k = 0;
    float best = fabsf(fr - frs[0]);
#pragma unroll
    for (int e = 1; e < NEXP; ++e) {
        float d = fabsf(fr - frs[e]);
        if (d < best) { best = d; k = e; }
    }
    return k;
}

// ================= K_prep: per-expert tables (A-frags + compact C) =================
// Per-expert table (TBL_BYTES):
//   0..7167  : 7 chunks x 1024B, f16 A-fragments (chunk = 64 lanes x 16B):
//     0      : A1 = W1^T, b1 folded at k=4 (x4=1.0); g=1 half all-zero
//     1..2   : A2 kf=0,1 — K-permuted: elem ei,g -> row kf*16+(ei&3)+8*(ei>>2)+4g
//     3..6   : A3 (t,kf)=3+t*2+kf — same K-permutation
//   7168..   : compact C floats [mat][32], idx = mat*32 + g*16 + r:
//     mat 0  : C2  = b2[(r&3)+8(r>>2)+4g]
//     mat 1,2: C30/C31 = b3 tiles 0/1
//     mat 3,4: W40/W41 = rowsum(W4) tiles 0/1
//     [160]  : b4s = sum(b4)
__global__ __launch_bounds__(256) void k_prep(const float* __restrict__ W1, const float* __restrict__ b1,
                                              const float* __restrict__ W2, const float* __restrict__ b2,
                                              const float* __restrict__ W3, const float* __restrict__ b3,
                                              const float* __restrict__ W4, const float* __restrict__ b4,
                                              char* __restrict__ tab) {
    int e = blockIdx.x;
    int tid = threadIdx.x;
    char* T = tab + (size_t)e * TBL_BYTES;

    __shared__ float psum[64][4];
    __shared__ float rs2[64];
    __shared__ float b4s_s;
    {   // W4 rowsum partials: 256 thr, each sums 16 floats
        int row = tid >> 2, q = tid & 3;
        const float* w = W4 + (size_t)e * 4096 + row * 64 + q * 16;
        f32x4 a = *(const f32x4*)(w + 0), b = *(const f32x4*)(w + 4);
        f32x4 c = *(const f32x4*)(w + 8), d = *(const f32x4*)(w + 12);
        psum[row][q] = (a.x + a.y + a.z + a.w) + (b.x + b.y + b.z + b.w)
                     + (c.x + c.y + c.z + c.w) + (d.x + d.y + d.z + d.w);
    }
    __syncthreads();
    if (tid < 64) {
        int l = tid, g = l >> 5, m = l & 31;
        rs2[l] = psum[l][0] + psum[l][1] + psum[l][2] + psum[l][3];
        float bp = b4[e * 64 + l];
#pragma unroll
        for (int d = 1; d < 64; d <<= 1) bp += __shfl_xor(bp, d, 64);
        if (l == 0) b4s_s = bp;

        // A1
        {
            f16x8 v;
#pragma unroll
            for (int ei = 0; ei < 8; ++ei) {
                int k = g * 8 + ei;
                float w = (k < 4) ? W1[e * 128 + k * 32 + m] : (k == 4 ? b1[e * 32 + m] : 0.f);
                v[ei] = (_Float16)w;
            }
            *(f16x8*)(T + 0 * 1024 + l * 16) = v;
        }
        // A2 (K-permuted)
#pragma unroll
        for (int kf = 0; kf < 2; ++kf) {
            f16x8 v;
#pragma unroll
            for (int ei = 0; ei < 8; ++ei) {
                int row = kf * 16 + (ei & 3) + 8 * (ei >> 2) + 4 * g;
                v[ei] = (_Float16)W2[e * 1024 + row * 32 + m];
            }
            *(f16x8*)(T + (1 + kf) * 1024 + l * 16) = v;
        }
        // A3 (K-permuted)
#pragma unroll
        for (int t = 0; t < 2; ++t)
#pragma unroll
            for (int kf = 0; kf < 2; ++kf) {
                f16x8 v;
#pragma unroll
                for (int ei = 0; ei < 8; ++ei) {
                    int row = kf * 16 + (ei & 3) + 8 * (ei >> 2) + 4 * g;
                    v[ei] = (_Float16)W3[e * 2048 + row * 64 + t * 32 + m];
                }
                *(f16x8*)(T + (3 + t * 2 + kf) * 1024 + l * 16) = v;
            }
    }
    __syncthreads();
    if (tid < 32) {
        int g = tid >> 4, r = tid & 15;
        int row = (r & 3) + 8 * (r >> 2) + 4 * g;
        float* C = (float*)(T + 7168);
        C[0 * 32 + tid] = b2[e * 32 + row];
        C[1 * 32 + tid] = b3[e * 64 + row];
        C[2 * 32 + tid] = b3[e * 64 + 32 + row];
        C[3 * 32 + tid] = rs2[row];
        C[4 * 32 + tid] = rs2[32 + row];
        if (tid == 0) C[160] = b4s_s;
    }
}

// ================= K_main: block-local bucket + MFMA MLP, one pass =================
__global__ __launch_bounds__(FTHR, 4) void k_main(const float* __restrict__ feat, int n,
                                                  const char* __restrict__ tab,
                                                  float* __restrict__ out) {
    __shared__ uint2 bx[PADSLK];                // packed f16 features per slot (incl. pad)
    __shared__ unsigned short bidx[PADSLK];     // local sample index per slot
    __shared__ float cls[NEXP * CLS_STRIDE];    // all-expert compact C tables
    __shared__ int lcnt[NEXP];
    __shared__ int pbase[NEXP];
    __shared__ int wbase[RPH][8][NEXP];         // [phase][wave][expert] offsets
    __shared__ unsigned char tile_e[MAXT];
    __shared__ short tile_s[MAXT];
    __shared__ unsigned char tile_v[MAXT];
    __shared__ int nt_s;

    int bid = blockIdx.x, tid = threadIdx.x;
    int wid = tid >> 6, lane = tid & 63, g = lane >> 5, m = lane & 31;
    int gbase = bid * SBLK;

    if (tid < NEXP) lcnt[tid] = 0;
    {   // zero the full padded bucket range (pad slots must be benign)
        uint2 z = {0u, 0u};
#pragma unroll
        for (int q = 0; q < 5; ++q) {
            int o = q * FTHR + tid;
            if (o < PADSLK) bx[o] = z;
        }
    }
    {   // stage all-expert compact C into LDS (1449 floats)
        const float* tf = (const float*)tab;
        for (int idx = tid; idx < NEXP * 161; idx += FTHR) {
            int e = idx / 161, o = idx - e * 161;
            cls[e * CLS_STRIDE + o] = tf[e * (TBL_BYTES / 4) + 1792 + o];
        }
    }
    __syncthreads();

    // ---- phase 1: classify + per-wave counts ----
    int kk[RPH], rk[RPH];
    uint2 xw[RPH];
#pragma unroll
    for (int r = 0; r < RPH; ++r) {
        int i = gbase + r * FTHR + tid;
        int k = -1;
        uint2 w = {0u, 0u};
        if (i < n) {
            const float* f = feat + (size_t)i * 5;
            k = expert_of(f[0]);
            w.x = (unsigned)pk(f[1], f[2]);
            w.y = (unsigned)pk(f[3], f[4]);
        }
        kk[r] = k; xw[r] = w;
        unsigned long long myM = 0;
#pragma unroll
        for (int e = 0; e < NEXP; ++e) {
            unsigned long long mm = __ballot(k == e);
            if (k == e) myM = mm;
            if (lane == 0) {
                int c = __popcll(mm);
                wbase[r][wid][e] = c ? atomicAdd(&lcnt[e], c) : 0;
            }
        }
        rk[r] = __popcll(myM & ((1ull << lane) - 1ull));
    }
    __syncthreads();

    // ---- tile map: wave 0, 9-lane shuffle scan + parallel fill ----
    if (wid == 0) {
        int e = lane;
        int c = (e < NEXP) ? lcnt[e] : 0;
        int ntl = (c + 31) >> 5;
        int padc = ntl << 5;
        int sp = padc, st = ntl;
#pragma unroll
        for (int d = 1; d < 16; d <<= 1) {
            int a = __shfl_up(sp, d, 64);
            int b = __shfl_up(st, d, 64);
            if (lane >= d) { sp += a; st += b; }
        }
        if (e < NEXP) {
            int pb = sp - padc, tb = st - ntl;
            pbase[e] = pb;
            for (int j = 0; j < ntl; ++j) {
                tile_e[tb + j] = (unsigned char)e;
                tile_s[tb + j] = (short)(pb + j * 32);
                int v = c - j * 32;
                tile_v[tb + j] = (unsigned char)(v > 32 ? 32 : v);
            }
            if (e == NEXP - 1) nt_s = st;   // inclusive total tiles
        }
    }
    __syncthreads();

    // ---- phase 2: scatter into LDS buckets ----
#pragma unroll
    for (int r = 0; r < RPH; ++r) {
        int k = kk[r];
        if (k >= 0) {
            int slot = pbase[k] + wbase[r][wid][k] + rk[r];
            bx[slot] = xw[r];
            bidx[slot] = (unsigned short)(r * FTHR + tid);
        }
    }
    __syncthreads();

    // ---- MLP: contiguous tile range per wave; A & W4 hoisted per expert-run ----
    int nt = nt_s;
    int t0 = (wid * nt) >> 3, t1 = ((wid + 1) * nt) >> 3;
    int cur_e = -1;
    f16x8 A1 = {}, A2a = {}, A2b = {}, A30a = {}, A30b = {}, A31a = {}, A31b = {};
    f32x16 W40r = zero16(), W41r = zero16();
    float b4v = 0.f;
    const float* Cc = cls;
    for (int t = t0; t < t1; ++t) {
        int e = __builtin_amdgcn_readfirstlane((int)tile_e[t]);
        if (e != cur_e) {
            cur_e = e;
            const char* T = tab + (size_t)e * TBL_BYTES;
            A1 = *(const f16x8*)(T + 0 * 1024 + lane * 16);
            A2a = *(const f16x8*)(T + 1 * 1024 + lane * 16);
            A2b = *(const f16x8*)(T + 2 * 1024 + lane * 16);
            A30a = *(const f16x8*)(T + 3 * 1024 + lane * 16);
            A30b = *(const f16x8*)(T + 4 * 1024 + lane * 16);
            A31a = *(const f16x8*)(T + 5 * 1024 + lane * 16);
            A31b = *(const f16x8*)(T + 6 * 1024 + lane * 16);
            Cc = cls + e * CLS_STRIDE + g * 16;
            {
                Q4 q;
                const float* c = Cc + 3 * 32;
                q.a = *(const f32x4*)(c + 0); q.b = *(const f32x4*)(c + 4);
                q.c = *(const f32x4*)(c + 8); q.d = *(const f32x4*)(c + 12);
                W40r = __builtin_bit_cast(f32x16, q);
                const float* c2 = Cc + 4 * 32;
                q.a = *(const f32x4*)(c2 + 0); q.b = *(const f32x4*)(c2 + 4);
                q.c = *(const f32x4*)(c2 + 8); q.d = *(const f32x4*)(c2 + 12);
                W41r = __builtin_bit_cast(f32x16, q);
            }
            b4v = cls[e * CLS_STRIDE + 160];
        }
        auto ldC = [&](int mat) -> f32x16 {
            const float* c = Cc + mat * 32;
            Q4 q;
            q.a = *(const f32x4*)(c + 0);
            q.b = *(const f32x4*)(c + 4);
            q.c = *(const f32x4*)(c + 8);
            q.d = *(const f32x4*)(c + 12);
            return __builtin_bit_cast(f32x16, q);
        };

        int s = tile_s[t], v = tile_v[t];
        uint2 xv = bx[s + m];

        I4 b1i = {g ? 0 : (int)xv.x, g ? 0 : (int)xv.y, g ? 0 : 0x3C00, 0};
        f16x8 B1 = __builtin_bit_cast(f16x8, b1i);

        f32x16 d1 = __builtin_amdgcn_mfma_f32_32x32x16_f16(A1, B1, zero16(), 0, 0, 0);
#pragma unroll
        for (int r = 0; r < 16; ++r) d1[r] = fmaxf(d1[r], 0.f);
        I4 p0 = {pk(d1[0], d1[1]), pk(d1[2], d1[3]), pk(d1[4], d1[5]), pk(d1[6], d1[7])};
        I4 p1 = {pk(d1[8], d1[9]), pk(d1[10], d1[11]), pk(d1[12], d1[13]), pk(d1[14], d1[15])};
        f16x8 B2a = __builtin_bit_cast(f16x8, p0);
        f16x8 B2b = __builtin_bit_cast(f16x8, p1);

        f32x16 d2 = __builtin_amdgcn_mfma_f32_32x32x16_f16(A2a, B2a, ldC(0), 0, 0, 0);
        d2 = __builtin_amdgcn_mfma_f32_32x32x16_f16(A2b, B2b, d2, 0, 0, 0);
#pragma unroll
        for (int r = 0; r < 16; ++r) d2[r] = fmaxf(d2[r], 0.f);
        I4 q0 = {pk(d2[0], d2[1]), pk(d2[2], d2[3]), pk(d2[4], d2[5]), pk(d2[6], d2[7])};
        I4 q1 = {pk(d2[8], d2[9]), pk(d2[10], d2[11]), pk(d2[12], d2[13]), pk(d2[14], d2[15])};
        f16x8 B3a = __builtin_bit_cast(f16x8, q0);
        f16x8 B3b = __builtin_bit_cast(f16x8, q1);

        float acc = 0.f;
        {
            f32x16 d3 = __builtin_amdgcn_mfma_f32_32x32x16_f16(A30a, B3a, ldC(1), 0, 0, 0);
            d3 = __builtin_amdgcn_mfma_f32_32x32x16_f16(A30b, B3b, d3, 0, 0, 0);
#pragma unroll
            for (int r = 0; r < 16; ++r) acc += fmaxf(d3[r], 0.f) * W40r[r];
        }
        {
            f32x16 d3 = __builtin_amdgcn_mfma_f32_32x32x16_f16(A31a, B3a, ldC(2), 0, 0, 0);
            d3 = __builtin_amdgcn_mfma_f32_32x32x16_f16(A31b, B3b, d3, 0, 0, 0);
#pragma unroll
            for (int r = 0; r < 16; ++r) acc += fmaxf(d3[r], 0.f) * W41r[r];
        }
        acc += __shfl_xor(acc, 32, 64);
        float rres = acc + b4v;
        if (!g && m < v) out[gbase + (int)bidx[s + m]] = rres;
    }
}

// ---------------- fallback (ws too small): divergent, correct ----------------
__global__ __launch_bounds__(256) void k_fallback(const float* __restrict__ feat,
                                                  const float* __restrict__ W1, const float* __restrict__ b1,
                                                  const float* __restrict__ W2, const float* __restrict__ b2,
                                                  const float* __restrict__ W3, const float* __restrict__ b3,
                                                  const float* __restrict__ W4, const float* __restrict__ b4,
                                                  float* __restrict__ out, int n) {
    int i = blockIdx.x * 256 + threadIdx.x;
    if (i >= n) return;
    const float* f = feat + (size_t)i * 5;
    int e = expert_of(f[0]);
    float x0 = f[1], x1 = f[2], x2 = f[3], x3 = f[4];
    float h1[32], h2[32], h3[64];
    for (int j = 0; j < 32; ++j) {
        float a = b1[e * 32 + j];
        a += x0 * W1[e * 128 + 0 * 32 + j];
        a += x1 * W1[e * 128 + 1 * 32 + j];
        a += x2 * W1[e * 128 + 2 * 32 + j];
        a += x3 * W1[e * 128 + 3 * 32 + j];
        h1[j] = fmaxf(a, 0.f);
    }
    for (int j = 0; j < 32; ++j) h2[j] = b2[e * 32 + j];
    for (int i2 = 0; i2 < 32; ++i2)
        for (int j = 0; j < 32; ++j) h2[j] += h1[i2] * W2[e * 1024 + i2 * 32 + j];
    for (int j = 0; j < 32; ++j) h2[j] = fmaxf(h2[j], 0.f);
    for (int j = 0; j < 64; ++j) h3[j] = b3[e * 64 + j];
    for (int i2 = 0; i2 < 32; ++i2)
        for (int j = 0; j < 64; ++j) h3[j] += h2[i2] * W3[e * 2048 + i2 * 64 + j];
    float pred = 0.f;
    for (int o = 0; o < 64; ++o) pred += b4[e * 64 + o];
    for (int j = 0; j < 64; ++j) {
        float rsum = 0.f;
        for (int o = 0; o < 64; ++o) rsum += W4[e * 4096 + j * 64 + o];
        pred += fmaxf(h3[j], 0.f) * rsum;
    }
    out[i] = pred;
}

extern "C" void kernel_launch(void* const* d_in, const int* in_sizes, int n_in,
                              void* d_out, int out_size, void* d_ws, size_t ws_size,
                              hipStream_t stream) {
    const float* feat = (const float*)d_in[0];
    const float* W1 = (const float*)d_in[1];
    const float* b1 = (const float*)d_in[2];
    const float* W2 = (const float*)d_in[3];
    const float* b2 = (const float*)d_in[4];
    const float* W3 = (const float*)d_in[5];
    const float* b3 = (const float*)d_in[6];
    const float* W4 = (const float*)d_in[7];
    const float* b4 = (const float*)d_in[8];
    float* out = (float*)d_out;
    int n = in_sizes[0] / 5;

    const size_t need = (size_t)NEXP * TBL_BYTES;

    if (ws_size >= need) {
        char* tab = (char*)d_ws;
        k_prep<<<NEXP, 256, 0, stream>>>(W1, b1, W2, b2, W3, b3, W4, b4, tab);
        int nb = (n + SBLK - 1) / SBLK;
        k_main<<<nb, FTHR, 0, stream>>>(feat, n, tab, out);
    } else {
        k_fallback<<<(n + 255) / 256, 256, 0, stream>>>(feat, W1, b1, W2, b2, W3, b3, W4, b4, out, n);
    }
}